// Round 1
// baseline (1288.962 us; speedup 1.0000x reference)
//
#include <hip/hip_runtime.h>
#include <cstdint>
#include <cstddef>

// Problem constants (match reference: B=64, L=512, STEPS=20)
#define LDIM 512
#define BATCH 64
#define NSTEPS 20
#define ROWS_PER_BLOCK 16
#define BLOCKS_PER_MAT (LDIM / ROWS_PER_BLOCK) // 32
#define NTHREADS 256

// Sum across the 64-lane wave (xor butterfly -> all lanes hold the sum).
__device__ __forceinline__ float wave_reduce_sum(float v) {
  v += __shfl_xor(v, 32);
  v += __shfl_xor(v, 16);
  v += __shfl_xor(v, 8);
  v += __shfl_xor(v, 4);
  v += __shfl_xor(v, 2);
  v += __shfl_xor(v, 1);
  return v;
}

__device__ __forceinline__ float relu_f(float x) { return fmaxf(x, 0.0f); }
__device__ __forceinline__ float sign_f(float x) {
  return (x > 0.0f) ? 1.0f : ((x < 0.0f) ? -1.0f : 0.0f);
}

// ---------------------------------------------------------------------------
// K_init: Ah = scores (into d_out); MUsym = M ? 0.5*(sc+sc^T)-s : -1e30;
// seed partial sums of M .* scores (rowpart complete per row; colpart per-block slot).
// Block: 256 threads, owns 16 full rows of one batch matrix; thread tid covers
// cols {tid, tid+256}.
// ---------------------------------------------------------------------------
template <bool USE_USYM>
__global__ __launch_bounds__(NTHREADS) void k_init(
    const float* __restrict__ scores, const float* __restrict__ M,
    const float* __restrict__ s_ptr, float* __restrict__ Ah,
    float* __restrict__ MU, float* __restrict__ rowpart_out,
    float* __restrict__ colpart_out) {
  __shared__ float rowacc[ROWS_PER_BLOCK][4];
  const int tid = threadIdx.x;
  const int lane = tid & 63;
  const int wid = tid >> 6;
  const int b = blockIdx.x >> 5;        // / BLOCKS_PER_MAT
  const int rb = blockIdx.x & 31;       // % BLOCKS_PER_MAT
  const int rowbase = rb * ROWS_PER_BLOCK;
  const float sval = s_ptr[0];

  float cacc0 = 0.0f, cacc1 = 0.0f;
#pragma unroll
  for (int r = 0; r < ROWS_PER_BLOCK; r++) {
    const int i = rowbase + r;
    const size_t base = ((size_t)(b * LDIM + i)) * LDIM;
    const float sc0 = scores[base + tid];
    const float sc1 = scores[base + tid + 256];
    const float m0 = M[base + tid];
    const float m1 = M[base + tid + 256];
    Ah[base + tid] = sc0;
    Ah[base + tid + 256] = sc1;
    if (USE_USYM) {
      // transpose reads: per-thread 16 consecutive floats over the r-loop
      const float t0 = scores[((size_t)(b * LDIM + tid)) * LDIM + i];
      const float t1 = scores[((size_t)(b * LDIM + tid + 256)) * LDIM + i];
      MU[base + tid] = (m0 != 0.0f) ? (0.5f * (sc0 + t0) - sval) : -1e30f;
      MU[base + tid + 256] = (m1 != 0.0f) ? (0.5f * (sc1 + t1) - sval) : -1e30f;
    }
    const float c0 = m0 * sc0;
    const float c1 = m1 * sc1;
    float rp = wave_reduce_sum(c0 + c1);
    if (lane == 0) rowacc[r][wid] = rp;
    cacc0 += c0;
    cacc1 += c1;
  }
  __syncthreads();
  if (tid < ROWS_PER_BLOCK) {
    rowpart_out[(size_t)b * LDIM + rowbase + tid] =
        rowacc[tid][0] + rowacc[tid][1] + rowacc[tid][2] + rowacc[tid][3];
  }
  const size_t cslot = ((size_t)(b * BLOCKS_PER_MAT + rb)) * LDIM;
  colpart_out[cslot + tid] = cacc0;
  colpart_out[cslot + tid + 256] = cacc1;
}

// ---------------------------------------------------------------------------
// K_step: fused per-step kernel.
// Prologue (redundant per block): rs = 0.5*(rowpart+sum(colpart)), Lm_t update,
// lmsg into LDS; designated blocks (rb==0) persist Lm_t to global (parity).
// Main loop: elementwise A_hat update + partial sums of M .* Ah2.
// ---------------------------------------------------------------------------
template <bool USE_USYM>
__global__ __launch_bounds__(NTHREADS) void k_step(
    const float* __restrict__ scores, const float* __restrict__ M,
    const float* __restrict__ MU, float* __restrict__ Ah,
    const float* __restrict__ rho_p, const float* __restrict__ s_ptr,
    const float* __restrict__ w_ptr, const float* __restrict__ alpha_ptr,
    const float* __restrict__ belt_ptr, const float* __restrict__ lra_ptr,
    const float* __restrict__ lrb_ptr, const float* __restrict__ rowpart_in,
    const float* __restrict__ colpart_in, float* __restrict__ rowpart_out,
    float* __restrict__ colpart_out, const float* __restrict__ Lm_in,
    float* __restrict__ Lm_out, int t) {
  __shared__ float lmsgS[LDIM];
  __shared__ float rowacc[ROWS_PER_BLOCK][4];
  const int tid = threadIdx.x;
  const int lane = tid & 63;
  const int wid = tid >> 6;
  const int b = blockIdx.x >> 5;
  const int rb = blockIdx.x & 31;
  const int rowbase = rb * ROWS_PER_BLOCK;

  const float alpha = alpha_ptr[0];
  const float belt = belt_ptr[0];
  const float lra = lra_ptr[0];
  const float lrb = lrb_ptr[0];
  const float wv = w_ptr[0];
  const float a_t = alpha * powf(lra, (float)t);
  const float bmul = (t > 0) ? (belt * powf(lrb, (float)(t - 1))) : 0.0f;
  const float sval = USE_USYM ? 0.0f : s_ptr[0];

  // ---- prologue: Lm_t / lmsg for all 512 rows of this batch ----
#pragma unroll
  for (int h = 0; h < 2; h++) {
    const int i = tid + 256 * h;
    const float srow = rowpart_in[(size_t)b * LDIM + i];
    float scol = 0.0f;
    const size_t cbase = (size_t)b * BLOCKS_PER_MAT * LDIM + i;
#pragma unroll
    for (int rb2 = 0; rb2 < BLOCKS_PER_MAT; rb2++) {
      scol += colpart_in[cbase + (size_t)rb2 * LDIM];
    }
    const float rs = 0.5f * (srow + scol);
    const float rd = rs - 1.0f;
    float lm;
    if (t == 0) {
      lm = wv * relu_f(rd);
    } else {
      lm = Lm_in[(size_t)b * LDIM + i] + bmul * relu_f(rd);
    }
    lmsgS[i] = lm * sign_f(rd);
    if (rb == 0) Lm_out[(size_t)b * LDIM + i] = lm;
  }
  __syncthreads();

  const float lmj0 = lmsgS[tid];
  const float lmj1 = lmsgS[tid + 256];
  float cacc0 = 0.0f, cacc1 = 0.0f;

#pragma unroll
  for (int r = 0; r < ROWS_PER_BLOCK; r++) {
    const int i = rowbase + r;
    const size_t base = ((size_t)(b * LDIM + i)) * LDIM;
    const float lmi = lmsgS[i];
    const float ah0 = Ah[base + tid];
    const float ah1 = Ah[base + tid + 256];
    const float rho0 = rho_p[(size_t)i * LDIM + tid];
    const float rho1 = rho_p[(size_t)i * LDIM + tid + 256];
    float m0, m1, us0, us1;
    if (USE_USYM) {
      const float mu0 = MU[base + tid];
      const float mu1 = MU[base + tid + 256];
      m0 = (mu0 > -1e29f) ? 1.0f : 0.0f;
      m1 = (mu1 > -1e29f) ? 1.0f : 0.0f;
      us0 = (mu0 > -1e29f) ? mu0 : 0.0f;
      us1 = (mu1 > -1e29f) ? mu1 : 0.0f;
    } else {
      m0 = M[base + tid];
      m1 = M[base + tid + 256];
      const float sc0 = scores[base + tid];
      const float sc1 = scores[base + tid + 256];
      const float t0 = scores[((size_t)(b * LDIM + tid)) * LDIM + i];
      const float t1 = scores[((size_t)(b * LDIM + tid + 256)) * LDIM + i];
      us0 = 0.5f * (sc0 + t0) - sval;
      us1 = 0.5f * (sc1 + t1) - sval;
    }
    // A_hat2 = Ah + a_t*Ah*M*(usym - lmsg_i - lmsg_j) = Ah*(1 + a_t*g)
    const float g0 = m0 * (us0 - lmi - lmj0);
    const float g1 = m1 * (us1 - lmi - lmj1);
    const float u0 = ah0 * fmaf(a_t, g0, 1.0f);
    const float u1 = ah1 * fmaf(a_t, g1, 1.0f);
    // soft-threshold + clip-above-at-1 (x>=0 post-relu => 1-relu(1-x)=min(x,1))
    const float v0 = fminf(relu_f(fabsf(u0) - rho0 * a_t), 1.0f);
    const float v1 = fminf(relu_f(fabsf(u1) - rho1 * a_t), 1.0f);
    Ah[base + tid] = v0;
    Ah[base + tid + 256] = v1;
    const float c0 = m0 * v0;
    const float c1 = m1 * v1;
    float rp = wave_reduce_sum(c0 + c1);
    if (lane == 0) rowacc[r][wid] = rp;
    cacc0 += c0;
    cacc1 += c1;
  }
  __syncthreads();
  if (tid < ROWS_PER_BLOCK) {
    rowpart_out[(size_t)b * LDIM + rowbase + tid] =
        rowacc[tid][0] + rowacc[tid][1] + rowacc[tid][2] + rowacc[tid][3];
  }
  const size_t cslot = ((size_t)(b * BLOCKS_PER_MAT + rb)) * LDIM;
  colpart_out[cslot + tid] = cacc0;
  colpart_out[cslot + tid + 256] = cacc1;
}

// ---------------------------------------------------------------------------
// K_final: in-place A = 0.5*(Ah + Ah^T) .* M over tile pairs (64x64 tiles).
// Grid: BATCH * 36 upper-triangular tile pairs; block 256 threads.
// ---------------------------------------------------------------------------
__global__ __launch_bounds__(NTHREADS) void k_final(float* __restrict__ Ah,
                                                    const float* __restrict__ M) {
  __shared__ float At[64][65];
  __shared__ float Bt[64][65];
  const int b = blockIdx.x / 36;
  int rem = blockIdx.x % 36;
  int ti = 0;
  while (rem >= 8 - ti) {
    rem -= 8 - ti;
    ti++;
  }
  const int tj = ti + rem;
  const int tid = threadIdx.x;
  const int c = tid & 63;
  const int r0 = tid >> 6; // 4 rows per pass
  const size_t mb = (size_t)b * LDIM * LDIM;

#pragma unroll
  for (int k = 0; k < 16; k++) {
    const int r = 4 * k + r0;
    At[r][c] = Ah[mb + (size_t)(ti * 64 + r) * LDIM + tj * 64 + c];
    Bt[r][c] = Ah[mb + (size_t)(tj * 64 + r) * LDIM + ti * 64 + c];
  }
  __syncthreads();
#pragma unroll
  for (int k = 0; k < 16; k++) {
    const int r = 4 * k + r0;
    const size_t idx_ij = mb + (size_t)(ti * 64 + r) * LDIM + tj * 64 + c;
    const float mij = M[idx_ij];
    Ah[idx_ij] = 0.5f * (At[r][c] + Bt[c][r]) * mij;
    if (ti != tj) {
      const size_t idx_ji = mb + (size_t)(tj * 64 + r) * LDIM + ti * 64 + c;
      const float mji = M[idx_ji];
      Ah[idx_ji] = 0.5f * (Bt[r][c] + At[c][r]) * mji;
    }
  }
}

// ---------------------------------------------------------------------------
extern "C" void kernel_launch(void* const* d_in, const int* in_sizes, int n_in,
                              void* d_out, int out_size, void* d_ws,
                              size_t ws_size, hipStream_t stream) {
  const float* scores = (const float*)d_in[0];
  const float* M = (const float*)d_in[1];
  const float* s_p = (const float*)d_in[2];
  const float* w_p = (const float*)d_in[3];
  const float* rho = (const float*)d_in[4];
  const float* alpha_p = (const float*)d_in[5];
  const float* belt_p = (const float*)d_in[6];
  const float* lra_p = (const float*)d_in[7];
  const float* lrb_p = (const float*)d_in[8];
  float* Ah = (float*)d_out; // d_out doubles as the A_hat state buffer

  // workspace layout (all plain stores; no zeroing needed)
  char* ws = (char*)d_ws;
  size_t off = 0;
  auto walloc = [&](size_t bytes) -> float* {
    float* p = (float*)(ws + off);
    off += (bytes + 255) & ~(size_t)255;
    return p;
  };
  const size_t BL = (size_t)BATCH * LDIM;
  float* Lm[2];
  float* rowpart[2];
  float* colpart[2];
  Lm[0] = walloc(BL * 4);
  Lm[1] = walloc(BL * 4);
  rowpart[0] = walloc(BL * 4);
  rowpart[1] = walloc(BL * 4);
  colpart[0] = walloc(BL * BLOCKS_PER_MAT * 4);
  colpart[1] = walloc(BL * BLOCKS_PER_MAT * 4);
  const size_t mu_bytes = (size_t)BATCH * LDIM * LDIM * 4;
  const bool use_usym = (off + mu_bytes) <= ws_size;
  float* MU = use_usym ? walloc(mu_bytes) : nullptr;

  const dim3 blk(NTHREADS);
  const dim3 grid(BATCH * BLOCKS_PER_MAT); // 2048

  if (use_usym) {
    k_init<true><<<grid, blk, 0, stream>>>(scores, M, s_p, Ah, MU, rowpart[0],
                                           colpart[0]);
  } else {
    k_init<false><<<grid, blk, 0, stream>>>(scores, M, s_p, Ah, MU, rowpart[0],
                                            colpart[0]);
  }

  for (int t = 0; t < NSTEPS; t++) {
    const int pin = t & 1;          // partials written by previous kernel
    const int pout = (t + 1) & 1;   // partials for next step
    const int lm_in = (t - 1) & 1;  // Lm_{t-1} parity (unused at t==0)
    const int lm_out = t & 1;
    if (use_usym) {
      k_step<true><<<grid, blk, 0, stream>>>(
          scores, M, MU, Ah, rho, s_p, w_p, alpha_p, belt_p, lra_p, lrb_p,
          rowpart[pin], colpart[pin], rowpart[pout], colpart[pout],
          Lm[lm_in & 1], Lm[lm_out], t);
    } else {
      k_step<false><<<grid, blk, 0, stream>>>(
          scores, M, MU, Ah, rho, s_p, w_p, alpha_p, belt_p, lra_p, lrb_p,
          rowpart[pin], colpart[pin], rowpart[pout], colpart[pout],
          Lm[lm_in & 1], Lm[lm_out], t);
    }
  }

  k_final<<<dim3(BATCH * 36), blk, 0, stream>>>(Ah, M);
}